// Round 11
// baseline (249.102 us; speedup 1.0000x reference)
//
#include <hip/hip_runtime.h>
#include <hip/hip_fp16.h>

typedef unsigned short u16;
typedef __attribute__((ext_vector_type(8))) short bf16x8;
typedef __attribute__((ext_vector_type(4))) float f32x4;

#define T_SEQ 2048
#define DIM 1024
#define NB 4
#define NCH 16        // 128-row chunks for column-softmax reduce (= S tileM count)

__device__ __forceinline__ u16 f2bf(float f) {
  union { float f; unsigned u; } c; c.f = f;
  unsigned r = c.u + 0x7fffu + ((c.u >> 16) & 1u);
  return (u16)(r >> 16);
}

__device__ __forceinline__ void gload_lds16(const void* g, void* l) {
  __builtin_amdgcn_global_load_lds((const __attribute__((address_space(1))) void*)g,
                                   (__attribute__((address_space(3))) void*)l, 16, 0, 0);
}

// ---------------- LayerNorm: x (f32) -> x_norm (bf16) ----------------
__global__ __launch_bounds__(256) void ln_kernel(const float* __restrict__ x,
                                                 const float* __restrict__ gamma,
                                                 const float* __restrict__ beta,
                                                 u16* __restrict__ xn) {
  const int row = blockIdx.x;
  const int tid = threadIdx.x;
  const float4 v = *(const float4*)(x + (size_t)row * DIM + tid * 4);
  float s  = v.x + v.y + v.z + v.w;
  float ss = v.x * v.x + v.y * v.y + v.z * v.z + v.w * v.w;
#pragma unroll
  for (int o = 32; o > 0; o >>= 1) { s += __shfl_down(s, o); ss += __shfl_down(ss, o); }
  __shared__ float rs[4], rss[4];
  const int wid = tid >> 6, lane = tid & 63;
  if (lane == 0) { rs[wid] = s; rss[wid] = ss; }
  __syncthreads();
  s  = rs[0] + rs[1] + rs[2] + rs[3];
  ss = rss[0] + rss[1] + rss[2] + rss[3];
  const float mu = s * (1.f / DIM);
  const float var = ss * (1.f / DIM) - mu * mu;
  const float rstd = rsqrtf(var + 1e-5f);
  const float4 g  = *(const float4*)(gamma + tid * 4);
  const float4 be = *(const float4*)(beta + tid * 4);
  ushort4 o;
  o.x = f2bf((v.x - mu) * rstd * g.x + be.x);
  o.y = f2bf((v.y - mu) * rstd * g.y + be.y);
  o.z = f2bf((v.z - mu) * rstd * g.z + be.z);
  o.w = f2bf((v.w - mu) * rstd * g.w + be.w);
  *(ushort4*)(xn + (size_t)row * DIM + tid * 4) = o;
}

// ---------------- f32 -> bf16 convert for Wv, Wo ----------------------------
__global__ __launch_bounds__(256) void wcvt2(const float* __restrict__ wv,
                                             const float* __restrict__ wo,
                                             u16* __restrict__ dv,
                                             u16* __restrict__ dw) {
  const int sel = blockIdx.x >> 10;
  const size_t t = (size_t)(blockIdx.x & 1023) * 256 + threadIdx.x;
  const float* w = sel ? wo : wv;
  u16* d = sel ? dw : dv;
  const float4 v = *(const float4*)(w + t * 4);
  ushort4 u; u.x = f2bf(v.x); u.y = f2bf(v.y); u.z = f2bf(v.z); u.w = f2bf(v.w);
  *(ushort4*)(d + t * 4) = u;
}

// ------- transposed bf16 convert: WT[d][f] = bf16(W[f][d])  (Wq, Wk) --------
__global__ __launch_bounds__(256) void wtrT(const float* __restrict__ wq,
                                            const float* __restrict__ wk,
                                            u16* __restrict__ dqT,
                                            u16* __restrict__ dkT) {
  __shared__ u16 tile[64][72];
  const float* w = blockIdx.z ? wk : wq;
  u16* d = blockIdx.z ? dkT : dqT;
  const int f0 = blockIdx.y * 64, d0 = blockIdx.x * 64;
  const int t = threadIdx.x;
  const int tr = t >> 4, tc = (t & 15) * 4;
#pragma unroll
  for (int p = 0; p < 4; ++p) {
    const float4 v = *(const float4*)(w + (size_t)(f0 + tr + 16 * p) * DIM + d0 + tc);
    tile[tr + 16 * p][tc]     = f2bf(v.x);
    tile[tr + 16 * p][tc + 1] = f2bf(v.y);
    tile[tr + 16 * p][tc + 2] = f2bf(v.z);
    tile[tr + 16 * p][tc + 3] = f2bf(v.w);
  }
  __syncthreads();
#pragma unroll
  for (int p = 0; p < 4; ++p) {
    const int dr = tr + 16 * p;
    ushort4 u;
    u.x = tile[tc][dr]; u.y = tile[tc + 1][dr];
    u.z = tile[tc + 2][dr]; u.w = tile[tc + 3][dr];
    *(ushort4*)(d + (size_t)(d0 + dr) * DIM + f0 + tc) = u;
  }
}

// ======= m97-style GEMM: 128x128 tile, BK=64, 4 waves, single 32KB buffer ===
// C[M,N] = A[M,K]*B[N,K]^T. Swizzle: 16B slot s of row r holds source chunk
// s^(r&7) (pre-swizzled source address).
// EPI 0: bf16   1: fp16*scale + fused per-column masked (max,sumexp) partials
// EPI 3: f32, +bias[col], relu
// MSK 0: none   1: skip tile if tileM >= l[bz]
// MSK 4: skip tile if (tileM&2047) >= l[tileM>>11]  (row-batched M dim)
template <int EPI, int MSK>
__global__ __launch_bounds__(256, 4) void gemm97(
    const u16* __restrict__ A, const u16* __restrict__ B, void* __restrict__ Cv,
    int K, int lda, int ldb, int ldc,
    long sA, long sB, long sC, float scale,
    const float* __restrict__ bias,
    const int* __restrict__ lptr, float* __restrict__ mpQ, float* __restrict__ zpQ) {
  __shared__ __align__(16) u16 As[128 * 64];
  __shared__ __align__(16) u16 Bs[128 * 64];
  const int bz = blockIdx.z;
  const u16* Ab = A + (size_t)bz * sA;
  const u16* Bb = B + (size_t)bz * sB;

  const int nb = gridDim.x * gridDim.y;
  int bid = blockIdx.y * gridDim.x + blockIdx.x;
  bid = (bid & 7) * (nb >> 3) + (bid >> 3);
  const int gx = gridDim.x;
  const int tileN = (bid % gx) * 128;
  const int tileM = (bid / gx) * 128;

  const int t = threadIdx.x;

  if constexpr (MSK == 1) {
    if (tileM >= lptr[bz]) return;
  }
  if constexpr (MSK == 4) {
    if ((tileM & (T_SEQ - 1)) >= lptr[tileM >> 11]) return;
  }

  const int lane = t & 63;
  const int wid = t >> 6;
  const int wm = wid >> 1, wn = wid & 1;      // 2 x 2 waves

  const int r0s = t >> 3;
  const int sch = ((t & 7) ^ (r0s & 7)) * 8;

  const int frow = lane & 15, kg = lane >> 4, f7 = lane & 7;

  f32x4 acc[4][4] = {};

  for (int k0 = 0; k0 < K; k0 += 64) {
    if (k0) __syncthreads();
#pragma unroll
    for (int i = 0; i < 4; ++i) {
      const int e = i * 256 + t;
      const int row = i * 32 + r0s;
      gload_lds16(Ab + (size_t)(tileM + row) * lda + k0 + sch, &As[e * 8]);
      gload_lds16(Bb + (size_t)(tileN + row) * ldb + k0 + sch, &Bs[e * 8]);
    }
    __syncthreads();
#pragma unroll
    for (int h = 0; h < 2; ++h) {
      const int cs = (((h * 4 + kg) ^ f7)) * 8;
      bf16x8 af[4], bf[4];
#pragma unroll
      for (int i = 0; i < 4; ++i)
        af[i] = *(const bf16x8*)&As[(wm * 64 + i * 16 + frow) * 64 + cs];
#pragma unroll
      for (int j = 0; j < 4; ++j)
        bf[j] = *(const bf16x8*)&Bs[(wn * 64 + j * 16 + frow) * 64 + cs];
#pragma unroll
      for (int i = 0; i < 4; ++i)
#pragma unroll
        for (int j = 0; j < 4; ++j)
          acc[i][j] = __builtin_amdgcn_mfma_f32_16x16x32_bf16(af[i], bf[j], acc[i][j], 0, 0, 0);
    }
  }

  const int r0 = tileM + wm * 64 + (kg << 2);
  const int c0 = tileN + wn * 64 + frow;
#pragma unroll
  for (int i = 0; i < 4; ++i)
#pragma unroll
    for (int j = 0; j < 4; ++j)
#pragma unroll
      for (int r = 0; r < 4; ++r) {
        const int row = r0 + i * 16 + r, col = c0 + j * 16;
        const size_t idx = (size_t)row * ldc + col;
        float v = acc[i][j][r];
        if constexpr (EPI == 0) {
          ((u16*)Cv + (size_t)bz * sC)[idx] = f2bf(v);
        } else if constexpr (EPI == 1) {
          ((__half*)Cv + (size_t)bz * sC)[idx] = __float2half(v * scale);
        } else {
          v += bias[col];
          ((float*)Cv + (size_t)bz * sC)[idx] = fmaxf(v, 0.f);
        }
      }

  // ---- EPI 1: fused per-column (over rows i, masked i<L) max & sumexp ------
  if constexpr (EPI == 1) {
    const int L = lptr[bz];
    __shared__ float2 red[2][2][4][16];
    float Ms[4], Zs[4];
#pragma unroll
    for (int j = 0; j < 4; ++j) {
      float mj = -3e38f;
#pragma unroll
      for (int i = 0; i < 4; ++i)
#pragma unroll
        for (int r = 0; r < 4; ++r) {
          const int row = r0 + i * 16 + r;
          if (row < L) mj = fmaxf(mj, acc[i][j][r] * scale);
        }
      mj = fmaxf(mj, __shfl_xor(mj, 16, 64));
      mj = fmaxf(mj, __shfl_xor(mj, 32, 64));
      float zj = 0.f;
#pragma unroll
      for (int i = 0; i < 4; ++i)
#pragma unroll
        for (int r = 0; r < 4; ++r) {
          const int row = r0 + i * 16 + r;
          if (row < L) zj += __expf(acc[i][j][r] * scale - mj);
        }
      zj += __shfl_xor(zj, 16, 64);
      zj += __shfl_xor(zj, 32, 64);
      Ms[j] = mj; Zs[j] = zj;
    }
    if (lane < 16) {
#pragma unroll
      for (int j = 0; j < 4; ++j) red[wm][wn][j][frow] = make_float2(Ms[j], Zs[j]);
    }
    __syncthreads();
    if (wm == 0 && lane < 16) {
#pragma unroll
      for (int j = 0; j < 4; ++j) {
        const float2 a = red[0][wn][j][frow];
        const float2 b = red[1][wn][j][frow];
        const float M = fmaxf(a.x, b.x);
        const float Z = a.y * __expf(a.x - M) + b.y * __expf(b.x - M);
        const int col = tileN + wn * 64 + j * 16 + frow;
        const size_t o = ((size_t)(tileM >> 7) * NB + bz) * T_SEQ + col;
        mpQ[o] = M; zpQ[o] = Z;
      }
    }
  }
}

// ===== PV GEMM with fused P-build: A = exp(S - m_j)*rz_j staged on the fly ==
// y[b] = x_b + P_b @ Vt_b^T. A from S (fp16, batched), B = Vt (gload_lds,
// pre-swizzled source), C = y bf16, residual x. Dead tiles (tileM>=L): y = x.
__global__ __launch_bounds__(256, 4) void gemm_pv(
    const __half* __restrict__ Sg, const u16* __restrict__ Vt,
    u16* __restrict__ C, const float* __restrict__ x,
    const int* __restrict__ lptr,
    const float* __restrict__ mb, const float* __restrict__ rzb) {
  __shared__ __align__(16) u16 As[128 * 64];
  __shared__ __align__(16) u16 Bs[128 * 64];
  const int bz = blockIdx.z;
  const __half* Ab = Sg + (size_t)bz * T_SEQ * T_SEQ;
  const u16* Bb = Vt + (size_t)bz * T_SEQ;          // column offset into [1024][8192]
  const float* mp = mb + bz * T_SEQ;
  const float* rp = rzb + bz * T_SEQ;

  const int nb = gridDim.x * gridDim.y;
  int bid = blockIdx.y * gridDim.x + blockIdx.x;
  bid = (bid & 7) * (nb >> 3) + (bid >> 3);
  const int gx = gridDim.x;
  const int tileN = (bid % gx) * 128;
  const int tileM = (bid / gx) * 128;
  const int t = threadIdx.x;
  const int L = lptr[bz];

  if (tileM >= L) {                                 // P rows zero -> y = x
    const float* xb = x + (size_t)bz * T_SEQ * DIM;
    u16* yo = C + (size_t)bz * T_SEQ * DIM;
    for (int e = t; e < (128 * 128) / 8; e += 256) {
      const int row = tileM + (e >> 4);
      const int col = tileN + ((e & 15) << 3);
      const float4 v0 = *(const float4*)(xb + (size_t)row * DIM + col);
      const float4 v1 = *(const float4*)(xb + (size_t)row * DIM + col + 4);
      ushort4 o0; o0.x = f2bf(v0.x); o0.y = f2bf(v0.y); o0.z = f2bf(v0.z); o0.w = f2bf(v0.w);
      ushort4 o1; o1.x = f2bf(v1.x); o1.y = f2bf(v1.y); o1.z = f2bf(v1.z); o1.w = f2bf(v1.w);
      *(ushort4*)(yo + (size_t)row * DIM + col) = o0;
      *(ushort4*)(yo + (size_t)row * DIM + col + 4) = o1;
    }
    return;
  }

  const int lane = t & 63;
  const int wid = t >> 6;
  const int wm = wid >> 1, wn = wid & 1;

  const int r0s = t >> 3;
  const int sch = ((t & 7) ^ (r0s & 7)) * 8;        // B source swizzle
  const int asrc = (t & 7) * 8;                     // A source col within 64
  const int frow = lane & 15, kg = lane >> 4, f7 = lane & 7;

  f32x4 acc[4][4] = {};

  for (int k0 = 0; k0 < T_SEQ; k0 += 64) {
    if (k0) __syncthreads();
    // B: async global->LDS, pre-swizzled source
#pragma unroll
    for (int i = 0; i < 4; ++i) {
      const int row = i * 32 + r0s;
      gload_lds16(Bb + (size_t)(tileN + row) * 8192 + k0 + sch, &Bs[(i * 256 + t) * 8]);
    }
    // A: reg-stage P = exp(S - m_j) * rz_j  (bf16, swizzled ds_write)
    const int j0 = k0 + asrc;
    float mv[8], zv[8];
    *(float4*)&mv[0] = *(const float4*)(mp + j0);
    *(float4*)&mv[4] = *(const float4*)(mp + j0 + 4);
    *(float4*)&zv[0] = *(const float4*)(rp + j0);
    *(float4*)&zv[4] = *(const float4*)(rp + j0 + 4);
#pragma unroll
    for (int i = 0; i < 4; ++i) {
      const int row = i * 32 + r0s;
      const int grow = tileM + row;
      const float4 sv = *(const float4*)(Ab + (size_t)grow * T_SEQ + j0);  // 8 halfs
      const __half* hp = (const __half*)&sv;
      bf16x8 pv = {0, 0, 0, 0, 0, 0, 0, 0};
      if (grow < L) {
#pragma unroll
        for (int q = 0; q < 8; ++q)
          pv[q] = (short)f2bf(__expf(__half2float(hp[q]) - mv[q]) * zv[q]);
      }
      *(bf16x8*)&As[row * 64 + ((t & 7) ^ (row & 7)) * 8] = pv;
    }
    __syncthreads();
#pragma unroll
    for (int h = 0; h < 2; ++h) {
      const int cs = (((h * 4 + kg) ^ f7)) * 8;
      bf16x8 af[4], bf[4];
#pragma unroll
      for (int i = 0; i < 4; ++i)
        af[i] = *(const bf16x8*)&As[(wm * 64 + i * 16 + frow) * 64 + cs];
#pragma unroll
      for (int j = 0; j < 4; ++j)
        bf[j] = *(const bf16x8*)&Bs[(wn * 64 + j * 16 + frow) * 64 + cs];
#pragma unroll
      for (int i = 0; i < 4; ++i)
#pragma unroll
        for (int j = 0; j < 4; ++j)
          acc[i][j] = __builtin_amdgcn_mfma_f32_16x16x32_bf16(af[i], bf[j], acc[i][j], 0, 0, 0);
    }
  }

  // epilogue: y = acc + x (bf16)
  const float* xb = x + (size_t)bz * T_SEQ * DIM;
  u16* yo = C + (size_t)bz * T_SEQ * DIM;
  const int r0 = tileM + wm * 64 + (kg << 2);
  const int c0 = tileN + wn * 64 + frow;
#pragma unroll
  for (int i = 0; i < 4; ++i)
#pragma unroll
    for (int j = 0; j < 4; ++j)
#pragma unroll
      for (int r = 0; r < 4; ++r) {
        const int row = r0 + i * 16 + r, col = c0 + j * 16;
        const size_t idx = (size_t)row * DIM + col;
        yo[idx] = f2bf(acc[i][j][r] + xb[idx]);
      }
}

// ------- combine live chunk partials per column -> m, 1/Z -------------------
__global__ __launch_bounds__(256) void colreduce_comb(const float* __restrict__ mp,
                                                      const float* __restrict__ zp,
                                                      const int* __restrict__ l,
                                                      float* __restrict__ m,
                                                      float* __restrict__ rz) {
  const int b = blockIdx.y;
  const int j = blockIdx.x * 256 + threadIdx.x;
  const int L = l[b];
  float M = -3e38f, Z = 0.f;
  for (int c = 0; c < NCH && (c << 7) < L; ++c) {
    const size_t o = ((size_t)c * NB + b) * T_SEQ + j;
    const float mc = mp[o], zc = zp[o];
    const float nm = fmaxf(M, mc);
    Z = Z * __expf(M - nm) + zc * __expf(mc - nm);
    M = nm;
  }
  m[b * T_SEQ + j] = M;
  rz[b * T_SEQ + j] = 1.f / Z;
}

// ---------------------------------------------------------------------------
extern "C" void kernel_launch(void* const* d_in, const int* in_sizes, int n_in,
                              void* d_out, int out_size, void* d_ws, size_t ws_size,
                              hipStream_t stream) {
  (void)in_sizes; (void)n_in; (void)out_size; (void)ws_size;
  const float* x     = (const float*)d_in[0];
  const int*   l     = (const int*)d_in[1];
  const float* Wq    = (const float*)d_in[2];
  const float* Wk    = (const float*)d_in[3];
  const float* Wv    = (const float*)d_in[4];
  const float* Wo    = (const float*)d_in[5];
  const float* bo    = (const float*)d_in[6];
  const float* gamma = (const float*)d_in[7];
  const float* beta  = (const float*)d_in[8];

  char* ws = (char*)d_ws;
  const size_t MiB = 1024 * 1024;
  u16* xn  = (u16*)(ws);              // 16 MiB x_norm; later overwritten by y
  u16* wvb = (u16*)(ws + 16 * MiB);   // 2 MiB
  u16* wob = (u16*)(ws + 18 * MiB);   // 2 MiB
  u16* wqT = (u16*)(ws + 20 * MiB);   // 2 MiB  Wq^T bf16
  u16* wkT = (u16*)(ws + 22 * MiB);   // 2 MiB  Wk^T bf16
  u16* MpT = (u16*)(ws + 24 * MiB);   // 2 MiB  (Wq^T Wk)^T bf16
  u16* Qp  = (u16*)(ws + 26 * MiB);   // 16 MiB Q' = xn @ (Wq^T Wk)
  u16* Vt  = (u16*)(ws + 42 * MiB);   // 16 MiB V^T [1024][8192]
  float* mpart = (float*)(ws + 58 * MiB);               // 512 KiB
  float* zpart = (float*)(ws + 58 * MiB + 512 * 1024);  // 512 KiB
  float* mb  = (float*)(ws + 59 * MiB);
  float* rzb = (float*)(ws + 59 * MiB + 32 * 1024);
  u16* yb = xn;
  __half* S = (__half*)d_out;         // d_out doubles as the 32 MiB score scratch
  float* outp = (float*)d_out;

  const long TD = (long)T_SEQ * DIM, TT = (long)T_SEQ * T_SEQ;

  ln_kernel<<<NB * T_SEQ, 256, 0, stream>>>(x, gamma, beta, xn);
  wcvt2<<<2048, 256, 0, stream>>>(Wv, Wo, wvb, wob);
  wtrT<<<dim3(16, 16, 2), 256, 0, stream>>>(Wq, Wk, wqT, wkT);

  // M'^T[e,d] = sum_f Wk[f,e] Wq[f,d]   (C = wkT . wqT^T)  grid 8x8 = 64
  gemm97<0, 0><<<dim3(8, 8, 1), 256, 0, stream>>>(
      wkT, wqT, MpT, DIM, DIM, DIM, DIM, 0, 0, 0, 0.f, nullptr,
      nullptr, nullptr, nullptr);
  // Q' = xn @ M'  (B = M'^T)  [8192,1024]  grid 8x64 = 512  (dead row-tiles skip)
  gemm97<0, 4><<<dim3(8, 64, 1), 256, 0, stream>>>(
      xn, MpT, Qp, DIM, DIM, DIM, DIM, 0, 0, 0, 0.f, nullptr,
      l, nullptr, nullptr);
  // V^T = Wv_bf @ xn^T   [1024, 8192]   grid 64x8 = 512
  gemm97<0, 0><<<dim3(64, 8, 1), 256, 0, stream>>>(
      wvb, xn, Vt, DIM, DIM, DIM, 8192, 0, 0, 0, 0.f, nullptr,
      nullptr, nullptr, nullptr);
  // S[b] = (Q'_b @ xn_b^T)*scale -> fp16 + fused per-column partials
  // grid 16x16x4 (dead tiles skip; K operand is xn itself)
  gemm97<1, 1><<<dim3(16, 16, NB), 256, 0, stream>>>(
      Qp, xn, S, DIM, DIM, DIM, T_SEQ, TD, TD, TT, 0.03125f, nullptr,
      l, mpart, zpart);
  // combine live chunk partials -> m, 1/Z
  colreduce_comb<<<dim3(T_SEQ / 256, NB), 256, 0, stream>>>(mpart, zpart, l, mb, rzb);
  // y[b] = x_b + P_b @ Vt_b^T with P built in-stage from S   grid 8x16x4
  gemm_pv<<<dim3(8, 16, NB), 256, 0, stream>>>(S, Vt, yb, x, l, mb, rzb);
  // out = relu(y @ Wo^T + bo)  f32   grid 8x64 = 512
  gemm97<3, 0><<<dim3(8, 64, 1), 256, 0, stream>>>(
      yb, wob, outp, DIM, DIM, DIM, DIM, 0, 0, 0, 0.f, bo,
      nullptr, nullptr, nullptr);
}

// Round 12
// 200.985 us; speedup vs baseline: 1.2394x; 1.2394x over previous
//
#include <hip/hip_runtime.h>
#include <hip/hip_fp16.h>

typedef unsigned short u16;
typedef __attribute__((ext_vector_type(8))) short bf16x8;
typedef __attribute__((ext_vector_type(4))) float f32x4;

#define T_SEQ 2048
#define DIM 1024
#define NB 4
#define NCH 16        // 128-row chunks for column-softmax reduce

__device__ __forceinline__ u16 f2bf(float f) {
  union { float f; unsigned u; } c; c.f = f;
  unsigned r = c.u + 0x7fffu + ((c.u >> 16) & 1u);
  return (u16)(r >> 16);
}

__device__ __forceinline__ void gload_lds16(const void* g, void* l) {
  __builtin_amdgcn_global_load_lds((const __attribute__((address_space(1))) void*)g,
                                   (__attribute__((address_space(3))) void*)l, 16, 0, 0);
}

// ---------------- LayerNorm: x (f32) -> x_norm (bf16) ----------------
__global__ __launch_bounds__(256) void ln_kernel(const float* __restrict__ x,
                                                 const float* __restrict__ gamma,
                                                 const float* __restrict__ beta,
                                                 u16* __restrict__ xn) {
  const int row = blockIdx.x;
  const int tid = threadIdx.x;
  const float4 v = *(const float4*)(x + (size_t)row * DIM + tid * 4);
  float s  = v.x + v.y + v.z + v.w;
  float ss = v.x * v.x + v.y * v.y + v.z * v.z + v.w * v.w;
#pragma unroll
  for (int o = 32; o > 0; o >>= 1) { s += __shfl_down(s, o); ss += __shfl_down(ss, o); }
  __shared__ float rs[4], rss[4];
  const int wid = tid >> 6, lane = tid & 63;
  if (lane == 0) { rs[wid] = s; rss[wid] = ss; }
  __syncthreads();
  s  = rs[0] + rs[1] + rs[2] + rs[3];
  ss = rss[0] + rss[1] + rss[2] + rss[3];
  const float mu = s * (1.f / DIM);
  const float var = ss * (1.f / DIM) - mu * mu;
  const float rstd = rsqrtf(var + 1e-5f);
  const float4 g  = *(const float4*)(gamma + tid * 4);
  const float4 be = *(const float4*)(beta + tid * 4);
  ushort4 o;
  o.x = f2bf((v.x - mu) * rstd * g.x + be.x);
  o.y = f2bf((v.y - mu) * rstd * g.y + be.y);
  o.z = f2bf((v.z - mu) * rstd * g.z + be.z);
  o.w = f2bf((v.w - mu) * rstd * g.w + be.w);
  *(ushort4*)(xn + (size_t)row * DIM + tid * 4) = o;
}

// ---------------- f32 -> bf16 weight convert, all 4 weights in one launch ---
__global__ __launch_bounds__(256) void wcvt4(const float* __restrict__ wq,
                                             const float* __restrict__ wk,
                                             const float* __restrict__ wv,
                                             const float* __restrict__ wo,
                                             u16* __restrict__ dqk,
                                             u16* __restrict__ dv,
                                             u16* __restrict__ dw) {
  const int sel = blockIdx.x >> 10;
  const size_t t = (size_t)(blockIdx.x & 1023) * 256 + threadIdx.x;
  const float* w = (sel == 0) ? wq : (sel == 1) ? wk : (sel == 2) ? wv : wo;
  u16* d = (sel == 0) ? dqk : (sel == 1) ? (dqk + 1048576) : (sel == 2) ? dv : dw;
  const float4 v = *(const float4*)(w + t * 4);
  ushort4 u; u.x = f2bf(v.x); u.y = f2bf(v.y); u.z = f2bf(v.z); u.w = f2bf(v.w);
  *(ushort4*)(d + t * 4) = u;
}

// ======= m97-style GEMM: 128x128 tile, BK=64, 4 waves, single 32KB buffer ===
// (proven round-10 kernel; used for V^T, PV, Wo)
// EPI 0: bf16   2: bf16 + aux residual (batched f32)   3: f32, +bias[col], relu
// MSK 0: none   2 (PV): if tileM >= l[bz], emit y = bf16(x) and skip
template <int EPI, int MSK>
__global__ __launch_bounds__(256, 4) void gemm97(
    const u16* __restrict__ A, const u16* __restrict__ B, void* __restrict__ Cv,
    int K, int lda, int ldb, int ldc,
    long sA, long sB, long sC,
    const float* __restrict__ aux, long sAux,
    const int* __restrict__ lptr) {
  __shared__ __align__(16) u16 As[128 * 64];
  __shared__ __align__(16) u16 Bs[128 * 64];
  const int bz = blockIdx.z;
  const u16* Ab = A + (size_t)bz * sA;
  const u16* Bb = B + (size_t)bz * sB;

  const int nb = gridDim.x * gridDim.y;
  int bid = blockIdx.y * gridDim.x + blockIdx.x;
  bid = (bid & 7) * (nb >> 3) + (bid >> 3);
  const int gx = gridDim.x;
  const int tileN = (bid % gx) * 128;
  const int tileM = (bid / gx) * 128;

  const int t = threadIdx.x;

  if constexpr (MSK == 2) {
    if (tileM >= lptr[bz]) {                  // P rows zero -> y = x
      const float* xb = aux + (size_t)bz * sAux;
      u16* yo = (u16*)Cv + (size_t)bz * sC;
      for (int e = t; e < (128 * 128) / 8; e += 256) {
        const int row = tileM + (e >> 4);
        const int col = tileN + ((e & 15) << 3);
        const float4 v0 = *(const float4*)(xb + (size_t)row * ldc + col);
        const float4 v1 = *(const float4*)(xb + (size_t)row * ldc + col + 4);
        ushort4 o0; o0.x = f2bf(v0.x); o0.y = f2bf(v0.y); o0.z = f2bf(v0.z); o0.w = f2bf(v0.w);
        ushort4 o1; o1.x = f2bf(v1.x); o1.y = f2bf(v1.y); o1.z = f2bf(v1.z); o1.w = f2bf(v1.w);
        *(ushort4*)(yo + (size_t)row * ldc + col) = o0;
        *(ushort4*)(yo + (size_t)row * ldc + col + 4) = o1;
      }
      return;
    }
  }

  const int lane = t & 63;
  const int wid = t >> 6;
  const int wm = wid >> 1, wn = wid & 1;      // 2 x 2 waves

  const int r0s = t >> 3;
  const int sch = ((t & 7) ^ (r0s & 7)) * 8;

  const int frow = lane & 15, kg = lane >> 4, f7 = lane & 7;

  f32x4 acc[4][4] = {};

  for (int k0 = 0; k0 < K; k0 += 64) {
    if (k0) __syncthreads();
#pragma unroll
    for (int i = 0; i < 4; ++i) {
      const int e = i * 256 + t;
      const int row = i * 32 + r0s;
      gload_lds16(Ab + (size_t)(tileM + row) * lda + k0 + sch, &As[e * 8]);
      gload_lds16(Bb + (size_t)(tileN + row) * ldb + k0 + sch, &Bs[e * 8]);
    }
    __syncthreads();
#pragma unroll
    for (int h = 0; h < 2; ++h) {
      const int cs = (((h * 4 + kg) ^ f7)) * 8;
      bf16x8 af[4], bf[4];
#pragma unroll
      for (int i = 0; i < 4; ++i)
        af[i] = *(const bf16x8*)&As[(wm * 64 + i * 16 + frow) * 64 + cs];
#pragma unroll
      for (int j = 0; j < 4; ++j)
        bf[j] = *(const bf16x8*)&Bs[(wn * 64 + j * 16 + frow) * 64 + cs];
#pragma unroll
      for (int i = 0; i < 4; ++i)
#pragma unroll
        for (int j = 0; j < 4; ++j)
          acc[i][j] = __builtin_amdgcn_mfma_f32_16x16x32_bf16(af[i], bf[j], acc[i][j], 0, 0, 0);
    }
  }

  const int r0 = tileM + wm * 64 + (kg << 2);
  const int c0 = tileN + wn * 64 + frow;
#pragma unroll
  for (int i = 0; i < 4; ++i)
#pragma unroll
    for (int j = 0; j < 4; ++j)
#pragma unroll
      for (int r = 0; r < 4; ++r) {
        const int row = r0 + i * 16 + r, col = c0 + j * 16;
        const size_t idx = (size_t)row * ldc + col;
        float v = acc[i][j][r];
        if constexpr (EPI == 0) {
          ((u16*)Cv + (size_t)bz * sC)[idx] = f2bf(v);
        } else if constexpr (EPI == 2) {
          v += (aux + (size_t)bz * sAux)[idx];
          ((u16*)Cv + (size_t)bz * sC)[idx] = f2bf(v);
        } else {
          v += aux[col];
          ((float*)Cv + (size_t)bz * sC)[idx] = fmaxf(v, 0.f);
        }
      }
}

// ==== wide-wave GEMM: BM=128 x BN=256, 4 waves (2x2), wave tile 64x128 ======
// acc[4][8] (128 VGPR), BK=64, single 48KB LDS buffer, 2 blocks/CU.
// 2x FLOP per barrier and 0.75x LDS traffic per FLOP vs the 128^2 kernel.
// EPI 0: bf16   1: fp16*scale + fused per-column masked (max,sumexp) partials
// MSK 1: skip tile if tileM >= l[bz]
// MSK 3 (QK): skip Q-half tiles (tileN < DIM) whose rows are all >= l[batch]
template <int EPI, int MSK>
__global__ __launch_bounds__(256, 2) void gemm_bw(
    const u16* __restrict__ A, const u16* __restrict__ B, void* __restrict__ Cv,
    int K, int lda, int ldb, int ldc,
    long sA, long sB, long sC, float scale,
    const int* __restrict__ lptr, float* __restrict__ mpQ, float* __restrict__ zpQ) {
  __shared__ __align__(16) u16 As[128 * 64];   // 16 KB
  __shared__ __align__(16) u16 Bs[256 * 64];   // 32 KB
  const int bz = blockIdx.z;
  const u16* Ab = A + (size_t)bz * sA;
  const u16* Bb = B + (size_t)bz * sB;

  const int nb = gridDim.x * gridDim.y;
  int bid = blockIdx.y * gridDim.x + blockIdx.x;
  bid = (bid & 7) * (nb >> 3) + (bid >> 3);
  const int gx = gridDim.x;
  const int tileN = (bid % gx) * 256;
  const int tileM = (bid / gx) * 128;

  const int t = threadIdx.x;

  if constexpr (MSK == 1) {
    if (tileM >= lptr[bz]) return;
  }
  if constexpr (MSK == 3) {
    if (((tileM & (T_SEQ - 1)) >= lptr[tileM >> 11]) && tileN < DIM) return;
  }

  const int lane = t & 63;
  const int wid = t >> 6;
  const int wm = wid >> 1, wn = wid & 1;      // 2M x 2N waves

  const int r0s = t >> 3;
  const int sch = ((t & 7) ^ (r0s & 7)) * 8;

  const int frow = lane & 15, kg = lane >> 4, f7 = lane & 7;

  f32x4 acc[4][8] = {};

  for (int k0 = 0; k0 < K; k0 += 64) {
    if (k0) __syncthreads();
#pragma unroll
    for (int i = 0; i < 4; ++i) {
      const int row = i * 32 + r0s;
      gload_lds16(Ab + (size_t)(tileM + row) * lda + k0 + sch, &As[(i * 256 + t) * 8]);
    }
#pragma unroll
    for (int i = 0; i < 8; ++i) {
      const int row = i * 32 + r0s;
      gload_lds16(Bb + (size_t)(tileN + row) * ldb + k0 + sch, &Bs[(i * 256 + t) * 8]);
    }
    __syncthreads();
#pragma unroll
    for (int h = 0; h < 2; ++h) {
      const int cs = (((h * 4 + kg) ^ f7)) * 8;
      bf16x8 af[4], bf[8];
#pragma unroll
      for (int i = 0; i < 4; ++i)
        af[i] = *(const bf16x8*)&As[(wm * 64 + i * 16 + frow) * 64 + cs];
#pragma unroll
      for (int j = 0; j < 8; ++j)
        bf[j] = *(const bf16x8*)&Bs[(wn * 128 + j * 16 + frow) * 64 + cs];
#pragma unroll
      for (int i = 0; i < 4; ++i)
#pragma unroll
        for (int j = 0; j < 8; ++j)
          acc[i][j] = __builtin_amdgcn_mfma_f32_16x16x32_bf16(af[i], bf[j], acc[i][j], 0, 0, 0);
    }
  }

  const int r0 = tileM + wm * 64 + (kg << 2);
  const int c0 = tileN + wn * 128 + frow;
#pragma unroll
  for (int i = 0; i < 4; ++i)
#pragma unroll
    for (int j = 0; j < 8; ++j)
#pragma unroll
      for (int r = 0; r < 4; ++r) {
        const int row = r0 + i * 16 + r, col = c0 + j * 16;
        const size_t idx = (size_t)row * ldc + col;
        const float v = acc[i][j][r];
        if constexpr (EPI == 0) {
          ((u16*)Cv + (size_t)bz * sC)[idx] = f2bf(v);
        } else {
          ((__half*)Cv + (size_t)bz * sC)[idx] = __float2half(v * scale);
        }
      }

  // ---- EPI 1: fused per-column (over rows i, masked i<L) max & sumexp ------
  if constexpr (EPI == 1) {
    const int L = lptr[bz];
    __shared__ float2 red[2][2][8][16];   // [wm][wn][j][frow]
    float Ms[8], Zs[8];
#pragma unroll
    for (int j = 0; j < 8; ++j) {
      float mj = -3e38f;
#pragma unroll
      for (int i = 0; i < 4; ++i)
#pragma unroll
        for (int r = 0; r < 4; ++r) {
          const int row = r0 + i * 16 + r;
          if (row < L) mj = fmaxf(mj, acc[i][j][r] * scale);
        }
      mj = fmaxf(mj, __shfl_xor(mj, 16, 64));
      mj = fmaxf(mj, __shfl_xor(mj, 32, 64));
      float zj = 0.f;
#pragma unroll
      for (int i = 0; i < 4; ++i)
#pragma unroll
        for (int r = 0; r < 4; ++r) {
          const int row = r0 + i * 16 + r;
          if (row < L) zj += __expf(acc[i][j][r] * scale - mj);
        }
      zj += __shfl_xor(zj, 16, 64);
      zj += __shfl_xor(zj, 32, 64);
      Ms[j] = mj; Zs[j] = zj;
    }
    if (lane < 16) {
#pragma unroll
      for (int j = 0; j < 8; ++j) red[wm][wn][j][frow] = make_float2(Ms[j], Zs[j]);
    }
    __syncthreads();
    if (wm == 0 && lane < 16) {
#pragma unroll
      for (int j = 0; j < 8; ++j) {
        const float2 a = red[0][wn][j][frow];
        const float2 b = red[1][wn][j][frow];
        const float M = fmaxf(a.x, b.x);
        const float Z = a.y * __expf(a.x - M) + b.y * __expf(b.x - M);
        const int col = tileN + wn * 128 + j * 16 + frow;
        const size_t o = ((size_t)(tileM >> 7) * NB + bz) * T_SEQ + col;
        mpQ[o] = M; zpQ[o] = Z;
      }
    }
  }
}

// ------- combine live chunk partials per column -> m, 1/Z -------------------
__global__ __launch_bounds__(256) void colreduce_comb(const float* __restrict__ mp,
                                                      const float* __restrict__ zp,
                                                      const int* __restrict__ l,
                                                      float* __restrict__ m,
                                                      float* __restrict__ rz) {
  const int b = blockIdx.y;
  const int j = blockIdx.x * 256 + threadIdx.x;
  const int L = l[b];
  float M = -3e38f, Z = 0.f;
  for (int c = 0; c < NCH && (c << 7) < L; ++c) {
    const size_t o = ((size_t)c * NB + b) * T_SEQ + j;
    const float mc = mp[o], zc = zp[o];
    const float nm = fmaxf(M, mc);
    Z = Z * __expf(M - nm) + zc * __expf(mc - nm);
    M = nm;
  }
  m[b * T_SEQ + j] = M;
  rz[b * T_SEQ + j] = 1.f / Z;
}

// ---------------- P = exp(S - m) / Z  (bf16, row-masked) -------------------
__global__ __launch_bounds__(256) void pbuild(const __half* __restrict__ S,
                                              const int* __restrict__ l,
                                              const float* __restrict__ m,
                                              const float* __restrict__ rz,
                                              u16* __restrict__ P) {
  const int b = blockIdx.x >> 11;
  const int i = blockIdx.x & (T_SEQ - 1);
  const int L = l[b];
  if (i >= ((L + 127) & ~127)) return;
  const int j0 = threadIdx.x * 8;
  const size_t off = ((size_t)blockIdx.x << 11) + j0;
  ushort4 o0, o1;
  if (i < L) {
    const __half* sp = S + off;
    const float* mp = m + b * T_SEQ + j0;
    const float* zp = rz + b * T_SEQ + j0;
    u16 tmp[8];
#pragma unroll
    for (int tt = 0; tt < 8; ++tt)
      tmp[tt] = f2bf(__expf(__half2float(sp[tt]) - mp[tt]) * zp[tt]);
    o0 = make_ushort4(tmp[0], tmp[1], tmp[2], tmp[3]);
    o1 = make_ushort4(tmp[4], tmp[5], tmp[6], tmp[7]);
  } else {
    o0 = make_ushort4(0, 0, 0, 0);
    o1 = make_ushort4(0, 0, 0, 0);
  }
  *(ushort4*)(P + off) = o0;
  *(ushort4*)(P + off + 4) = o1;
}

// ---------------------------------------------------------------------------
extern "C" void kernel_launch(void* const* d_in, const int* in_sizes, int n_in,
                              void* d_out, int out_size, void* d_ws, size_t ws_size,
                              hipStream_t stream) {
  (void)in_sizes; (void)n_in; (void)out_size; (void)ws_size;
  const float* x     = (const float*)d_in[0];
  const int*   l     = (const int*)d_in[1];
  const float* Wq    = (const float*)d_in[2];
  const float* Wk    = (const float*)d_in[3];
  const float* Wv    = (const float*)d_in[4];
  const float* Wo    = (const float*)d_in[5];
  const float* bo    = (const float*)d_in[6];
  const float* gamma = (const float*)d_in[7];
  const float* beta  = (const float*)d_in[8];

  char* ws = (char*)d_ws;
  const size_t MiB = 1024 * 1024;
  u16* xn   = (u16*)(ws);             // 16 MiB x_norm; later reused as y
  u16* wqkb = (u16*)(ws + 16 * MiB);  // 4 MiB: Wq rows then Wk rows (concat)
  u16* wvb  = (u16*)(ws + 20 * MiB);  // 2 MiB; later reused for softmax partials
  u16* wob  = (u16*)(ws + 22 * MiB);  // 2 MiB
  u16* QKb  = (u16*)(ws + 24 * MiB);  // 32 MiB: [8192][2048] Q|K; reused as P
  u16* Vt   = (u16*)(ws + 56 * MiB);  // 16 MiB: [1024][8192] V^T (all batches)
  float* mpart = (float*)(ws + 20 * MiB);                // 512 KiB (over dead wvb)
  float* zpart = (float*)(ws + 20 * MiB + 512 * 1024);   // 512 KiB
  float* mb  = (float*)(ws + 72 * MiB);
  float* rzb = (float*)(ws + 72 * MiB + 32 * 1024);
  u16* Pb = QKb;                      // P overwrites dead Q|K
  u16* yb = xn;
  __half* S = (__half*)d_out;         // d_out doubles as the 32 MiB score scratch
  float* outp = (float*)d_out;

  const long TD = (long)T_SEQ * DIM, TT = (long)T_SEQ * T_SEQ;
  const long TQK = (long)T_SEQ * 2048;

  ln_kernel<<<NB * T_SEQ, 256, 0, stream>>>(x, gamma, beta, xn);
  wcvt4<<<4096, 256, 0, stream>>>(Wq, Wk, Wv, Wo, wqkb, wvb, wob);

  // Q|K = xn @ [Wq;Wk]^T  [8192,2048]  grid 8x64 = 512 (dead Q-tiles skip)
  gemm_bw<0, 3><<<dim3(8, 64, 1), 256, 0, stream>>>(
      xn, wqkb, QKb, DIM, DIM, DIM, 2048, 0, 0, 0, 0.f,
      l, nullptr, nullptr);
  // V^T = Wv_bf @ xn^T   [1024, 8192]   grid 64x8 = 512
  gemm97<0, 0><<<dim3(64, 8, 1), 256, 0, stream>>>(
      wvb, xn, Vt, DIM, DIM, DIM, 8192, 0, 0, 0, nullptr, 0, nullptr);
  // S[b] = (Q_b @ K_b^T)*scale -> fp16, + fused per-column partial (m,z)
  // grid 8x16x4 = 512 (tiles with all rows masked skip; slots refill)
  gemm_bw<1, 1><<<dim3(8, 16, NB), 256, 0, stream>>>(
      QKb, QKb + 1024, S, DIM, 2048, 2048, T_SEQ, TQK, TQK, TT, 0.03125f,
      l, mpart, zpart);
  // combine live chunk partials -> m, 1/Z
  colreduce_comb<<<dim3(T_SEQ / 256, NB), 256, 0, stream>>>(mpart, zpart, l, mb, rzb);
  // P = exp(S-m)*rz (bf16), zero straddle band, skip fully-dead rows
  pbuild<<<NB * T_SEQ, 256, 0, stream>>>(S, l, mb, rzb, Pb);
  // y[b] = x_b + P_b @ Vt_b^T  [2048,1024] bf16  grid 8x16x4 = 512
  gemm97<2, 2><<<dim3(8, 16, NB), 256, 0, stream>>>(
      Pb, Vt, yb, T_SEQ, T_SEQ, 8192, DIM, TT, 2048, TD, x, TD, l);
  // out = relu(y @ Wo^T + bo)  f32   grid 8x64 = 512
  gemm97<3, 0><<<dim3(8, 64, 1), 256, 0, stream>>>(
      yb, wob, outp, DIM, DIM, DIM, DIM, 0, 0, 0, bo, 0, nullptr);
}